// Round 1
// baseline (2256.243 us; speedup 1.0000x reference)
//
#include <hip/hip_runtime.h>
#include <math.h>

#define N_NODES 50000
#define N_EDGES 800000
#define DF 128
#define EF 16
#define EH 64
#define NH 128
#define NC 40

// ---------------------------------------------------------------- K1: edge MLP
// ew[e] = sigmoid( relu(ef[e]@W1 + b1) @ W2 + b2 )
__global__ __launch_bounds__(256) void edge_mlp_kernel(
    const float* __restrict__ ef, const float* __restrict__ W1,
    const float* __restrict__ b1, const float* __restrict__ W2,
    const float* __restrict__ b2, float* __restrict__ ew)
{
    __shared__ float W1s[EF * EH];
    __shared__ float b1s[EH];
    __shared__ float W2s[EH];
    int t = threadIdx.x;
    for (int i = t; i < EF * EH; i += 256) W1s[i] = W1[i];
    if (t < EH) { b1s[t] = b1[t]; W2s[t] = W2[t]; }
    __syncthreads();

    int e = blockIdx.x * 256 + t;
    if (e >= N_EDGES) return;

    float f[EF];
    const float4* ef4 = (const float4*)(ef + (long)e * EF);
    #pragma unroll
    for (int i = 0; i < 4; ++i) {
        float4 v = ef4[i];
        f[4*i+0] = v.x; f[4*i+1] = v.y; f[4*i+2] = v.z; f[4*i+3] = v.w;
    }
    float s = 0.f;
    #pragma unroll 8
    for (int j = 0; j < EH; ++j) {
        float a = b1s[j];
        #pragma unroll
        for (int k = 0; k < EF; ++k) a += f[k] * W1s[k * EH + j];  // LDS broadcast
        s += fmaxf(a, 0.f) * W2s[j];
    }
    s += b2[0];
    ew[e] = 1.f / (1.f + expf(-s));
}

// ---------------------------------------------------------------- K2: h = x @ Wc1
// block = 128 threads (one per output column), 32 rows per block.
__global__ __launch_bounds__(128) void gemm1_kernel(
    const float* __restrict__ x, const float* __restrict__ Wc1,
    float* __restrict__ h)
{
    __shared__ float xs[32][DF];  // reads are wave-uniform -> broadcast, no pad needed
    int t = threadIdx.x;
    int r0 = blockIdx.x * 32;
    #pragma unroll
    for (int i = 0; i < 32; ++i) {
        int r = r0 + i;
        xs[i][t] = (r < N_NODES) ? x[(long)r * DF + t] : 0.f;
    }
    __syncthreads();
    float acc[32];
    #pragma unroll
    for (int i = 0; i < 32; ++i) acc[i] = 0.f;
    #pragma unroll 4
    for (int k = 0; k < DF; ++k) {
        float w = Wc1[k * NH + t];          // coalesced, L2-resident
        #pragma unroll
        for (int i = 0; i < 32; ++i) acc[i] += xs[i][k] * w;
    }
    #pragma unroll
    for (int i = 0; i < 32; ++i) {
        int r = r0 + i;
        if (r < N_NODES) h[(long)r * NH + t] = acc[i];
    }
}

// ---------------------------------------------------------------- K4: scatter1
// 32 threads per edge, float4 each: agg[dst] += h[src] * ew[e]
__global__ __launch_bounds__(256) void scatter1_kernel(
    const float* __restrict__ h, const float* __restrict__ ew,
    const int* __restrict__ dst, const int* __restrict__ src,
    float* __restrict__ agg)
{
    long g = (long)blockIdx.x * 256 + threadIdx.x;
    int e = (int)(g >> 5);
    int l = (int)(g & 31);
    if (e >= N_EDGES) return;
    float w = ew[e];
    int s = src[e], d = dst[e];
    float4 v = ((const float4*)h)[(long)s * (NH / 4) + l];  // 512B/edge coalesced
    float* o = agg + (long)d * NH + l * 4;
    atomicAdd(o + 0, v.x * w);
    atomicAdd(o + 1, v.y * w);
    atomicAdd(o + 2, v.z * w);
    atomicAdd(o + 3, v.w * w);
}

// ---------------------------------------------------------------- K5: h2 = relu(agg+bc1) @ Wc2
// block = 128 threads, 32 rows; thread -> (row = t>>2, 10 cols starting (t&3)*10)
__global__ __launch_bounds__(128) void gemm2_kernel(
    const float* __restrict__ agg, const float* __restrict__ bc1,
    const float* __restrict__ Wc2, float* __restrict__ h2)
{
    __shared__ float xs[32][NH + 1];  // +1 pad: row-varying reads below
    __shared__ float Ws[NH * NC];     // 20 KB
    int t = threadIdx.x;
    for (int i = t; i < NH * NC; i += 128) Ws[i] = Wc2[i];
    int r0 = blockIdx.x * 32;
    float bv = bc1[t];
    #pragma unroll
    for (int i = 0; i < 32; ++i) {
        int r = r0 + i;
        xs[i][t] = (r < N_NODES) ? fmaxf(agg[(long)r * NH + t] + bv, 0.f) : 0.f;
    }
    __syncthreads();

    int r  = t >> 2;
    int c0 = (t & 3) * 10;
    float acc[10];
    #pragma unroll
    for (int i = 0; i < 10; ++i) acc[i] = 0.f;
    #pragma unroll 4
    for (int k = 0; k < NH; ++k) {
        float xv = xs[r][k];
        #pragma unroll
        for (int i = 0; i < 10; ++i) acc[i] += xv * Ws[k * NC + c0 + i];
    }
    int rr = r0 + r;
    if (rr < N_NODES) {
        #pragma unroll
        for (int i = 0; i < 10; ++i) h2[(long)rr * NC + c0 + i] = acc[i];
    }
}

// ---------------------------------------------------------------- K6: scatter2
// 8 threads per edge, 5 floats each: out[dst] += h2[src] * ew[e]
__global__ __launch_bounds__(256) void scatter2_kernel(
    const float* __restrict__ h2, const float* __restrict__ ew,
    const int* __restrict__ dst, const int* __restrict__ src,
    float* __restrict__ out)
{
    long g = (long)blockIdx.x * 256 + threadIdx.x;
    int e = (int)(g >> 3);
    int l = (int)(g & 7);
    if (e >= N_EDGES) return;
    float w = ew[e];
    int s = src[e], d = dst[e];
    const float* hp = h2 + (long)s * NC + l * 5;
    float* op = out + (long)d * NC + l * 5;
    #pragma unroll
    for (int i = 0; i < 5; ++i) atomicAdd(op + i, hp[i] * w);
}

// ---------------------------------------------------------------- K7: out = -(log_softmax(out + bc2))
__global__ __launch_bounds__(256) void logsoftmax_kernel(
    float* __restrict__ out, const float* __restrict__ bc2)
{
    __shared__ float bs[NC];
    if (threadIdx.x < NC) bs[threadIdx.x] = bc2[threadIdx.x];
    __syncthreads();
    int r = blockIdx.x * 256 + threadIdx.x;
    if (r >= N_NODES) return;
    float v[NC];
    float m = -1e30f;
    #pragma unroll
    for (int i = 0; i < NC; ++i) {
        v[i] = out[(long)r * NC + i] + bs[i];
        m = fmaxf(m, v[i]);
    }
    float s = 0.f;
    #pragma unroll
    for (int i = 0; i < NC; ++i) s += expf(v[i] - m);
    float lse = m + logf(s);
    #pragma unroll
    for (int i = 0; i < NC; ++i) out[(long)r * NC + i] = lse - v[i];
}

// ----------------------------------------------------------------
extern "C" void kernel_launch(void* const* d_in, const int* in_sizes, int n_in,
                              void* d_out, int out_size, void* d_ws, size_t ws_size,
                              hipStream_t stream)
{
    const float* x         = (const float*)d_in[0];
    const float* edge_feat = (const float*)d_in[1];
    const float* W1        = (const float*)d_in[2];
    const float* b1        = (const float*)d_in[3];
    const float* W2        = (const float*)d_in[4];
    const float* b2        = (const float*)d_in[5];
    const float* Wc1       = (const float*)d_in[6];
    const float* bc1       = (const float*)d_in[7];
    const float* Wc2       = (const float*)d_in[8];
    const float* bc2       = (const float*)d_in[9];
    const int*   eidx      = (const int*)d_in[10];
    const int*   dst = eidx;             // edge_index[0]
    const int*   src = eidx + N_EDGES;   // edge_index[1]
    float* out = (float*)d_out;

    // workspace layout (all 16B-aligned): ew | h (reused as h2) | agg
    char* ws = (char*)d_ws;
    float* ew  = (float*)ws;                                 // E        (3.2 MB)
    float* h   = (float*)(ws + sizeof(float) * (long)N_EDGES);   // N*NH (25.6 MB)
    float* agg = h + (long)N_NODES * NH;                     // N*NH     (25.6 MB)
    float* h2  = h;  // h is dead after scatter1; reuse for h2 (N*NC = 8 MB)

    hipMemsetAsync(agg, 0, sizeof(float) * (long)N_NODES * NH, stream);
    hipMemsetAsync(out, 0, sizeof(float) * (long)N_NODES * NC, stream);

    edge_mlp_kernel<<<(N_EDGES + 255) / 256, 256, 0, stream>>>(edge_feat, W1, b1, W2, b2, ew);
    gemm1_kernel<<<(N_NODES + 31) / 32, 128, 0, stream>>>(x, Wc1, h);
    scatter1_kernel<<<(int)(((long)N_EDGES * 32) / 256), 256, 0, stream>>>(h, ew, dst, src, agg);
    gemm2_kernel<<<(N_NODES + 31) / 32, 128, 0, stream>>>(agg, bc1, Wc2, h2);
    scatter2_kernel<<<(int)(((long)N_EDGES * 8) / 256), 256, 0, stream>>>(h2, ew, dst, src, out);
    logsoftmax_kernel<<<(N_NODES + 255) / 256, 256, 0, stream>>>(out, bc2);
}

// Round 2
// 563.136 us; speedup vs baseline: 4.0066x; 4.0066x over previous
//
#include <hip/hip_runtime.h>
#include <math.h>

#define N_NODES 50000
#define N_EDGES 800000
#define DF 128
#define EF 16
#define EH 64
#define NH 128
#define NC 40

// ---------------------------------------------------------------- K1: edge MLP (+ fused dst-degree histogram)
// ew[e] = sigmoid( relu(ef[e]@W1 + b1) @ W2 + b2 );  deg[dst[e]] += 1
__global__ __launch_bounds__(256) void edge_mlp_kernel(
    const float* __restrict__ ef, const float* __restrict__ W1,
    const float* __restrict__ b1, const float* __restrict__ W2,
    const float* __restrict__ b2, const int* __restrict__ dst,
    float* __restrict__ ew, int* __restrict__ deg)
{
    __shared__ float W1s[EF * EH];
    __shared__ float b1s[EH];
    __shared__ float W2s[EH];
    int t = threadIdx.x;
    for (int i = t; i < EF * EH; i += 256) W1s[i] = W1[i];
    if (t < EH) { b1s[t] = b1[t]; W2s[t] = W2[t]; }
    __syncthreads();

    int e = blockIdx.x * 256 + t;
    if (e >= N_EDGES) return;

    float f[EF];
    const float4* ef4 = (const float4*)(ef + (long)e * EF);
    #pragma unroll
    for (int i = 0; i < 4; ++i) {
        float4 v = ef4[i];
        f[4*i+0] = v.x; f[4*i+1] = v.y; f[4*i+2] = v.z; f[4*i+3] = v.w;
    }
    float s = 0.f;
    #pragma unroll 8
    for (int j = 0; j < EH; ++j) {
        float a = b1s[j];
        #pragma unroll
        for (int k = 0; k < EF; ++k) a += f[k] * W1s[k * EH + j];
        s += fmaxf(a, 0.f) * W2s[j];
    }
    s += b2[0];
    ew[e] = 1.f / (1.f + expf(-s));
    atomicAdd(&deg[dst[e]], 1);   // avg contention 16 per counter — cheap
}

// ---------------------------------------------------------------- K2: h = x @ Wc1
__global__ __launch_bounds__(128) void gemm1_kernel(
    const float* __restrict__ x, const float* __restrict__ Wc1,
    float* __restrict__ h)
{
    __shared__ float xs[32][DF];  // column reads are wave-uniform -> broadcast
    int t = threadIdx.x;
    int r0 = blockIdx.x * 32;
    #pragma unroll
    for (int i = 0; i < 32; ++i) {
        int r = r0 + i;
        xs[i][t] = (r < N_NODES) ? x[(long)r * DF + t] : 0.f;
    }
    __syncthreads();
    float acc[32];
    #pragma unroll
    for (int i = 0; i < 32; ++i) acc[i] = 0.f;
    #pragma unroll 4
    for (int k = 0; k < DF; ++k) {
        float w = Wc1[k * NH + t];
        #pragma unroll
        for (int i = 0; i < 32; ++i) acc[i] += xs[i][k] * w;
    }
    #pragma unroll
    for (int i = 0; i < 32; ++i) {
        int r = r0 + i;
        if (r < N_NODES) h[(long)r * NH + t] = acc[i];
    }
}

// ---------------------------------------------------------------- K3: exclusive scan of deg -> rowptr (1 block)
__global__ __launch_bounds__(1024) void build_rowptr_kernel(
    const int* __restrict__ deg, int* __restrict__ rowptr)
{
    __shared__ int part[1024];
    const int CH = (N_NODES + 1023) / 1024;  // 49
    int t = threadIdx.x;
    int base = t * CH;
    int s = 0;
    for (int i = 0; i < CH; ++i) {
        int idx = base + i;
        if (idx < N_NODES) s += deg[idx];
    }
    part[t] = s;
    __syncthreads();
    // Hillis-Steele inclusive scan (reads complete before barrier, writes after)
    for (int o = 1; o < 1024; o <<= 1) {
        int v = (t >= o) ? part[t - o] : 0;
        __syncthreads();
        part[t] += v;
        __syncthreads();
    }
    int run = (t == 0) ? 0 : part[t - 1];
    for (int i = 0; i < CH; ++i) {
        int idx = base + i;
        if (idx < N_NODES) { rowptr[idx] = run; run += deg[idx]; }
    }
}

// ---------------------------------------------------------------- K4: CSR fill
// After this, rowptr[d] has been advanced to the END of segment d
// (start of segment d == rowptr[d-1], start of segment 0 == 0).
__global__ __launch_bounds__(256) void fill_csr_kernel(
    const int* __restrict__ dst, int* __restrict__ rowptr,
    int* __restrict__ eids)
{
    int e = blockIdx.x * 256 + threadIdx.x;
    if (e >= N_EDGES) return;
    int p = atomicAdd(&rowptr[dst[e]], 1);
    eids[p] = e;
}

// ---------------------------------------------------------------- K5: gather1 (replaces scatter1 + bias + relu)
// One wave per dst node: h1[d] = relu( sum_e ew[e]*h[src[e]] + bc1 )
__global__ __launch_bounds__(256) void gather1_kernel(
    const float* __restrict__ h, const float* __restrict__ ew,
    const int* __restrict__ src, const int* __restrict__ rp_end,
    const int* __restrict__ eids, const float* __restrict__ bc1,
    float* __restrict__ h1)
{
    int wid  = (blockIdx.x * 256 + threadIdx.x) >> 6;   // node id (grid sized exactly)
    int lane = threadIdx.x & 63;
    int end   = rp_end[wid];
    int start = (wid == 0) ? 0 : rp_end[wid - 1];
    float2 acc = make_float2(0.f, 0.f);
    for (int base = start; base < end; base += 64) {
        int n = min(64, end - base);
        int s = 0; float w = 0.f;
        if (base + lane < end) {
            int e = eids[base + lane];
            s = src[e];
            w = ew[e];
        }
        #pragma unroll 4
        for (int j = 0; j < n; ++j) {
            int   sj = __shfl(s, j, 64);
            float wj = __shfl(w, j, 64);
            float2 v = *(const float2*)(h + (long)sj * NH + lane * 2); // 512B/edge coalesced
            acc.x += wj * v.x;
            acc.y += wj * v.y;
        }
    }
    float2 o;
    o.x = fmaxf(acc.x + bc1[lane * 2 + 0], 0.f);
    o.y = fmaxf(acc.y + bc1[lane * 2 + 1], 0.f);
    *(float2*)(h1 + (long)wid * NH + lane * 2) = o;
}

// ---------------------------------------------------------------- K6: h2 = h1 @ Wc2 (h1 already biased+relu'd)
__global__ __launch_bounds__(128) void gemm2_kernel(
    const float* __restrict__ h1, const float* __restrict__ Wc2,
    float* __restrict__ h2)
{
    __shared__ float xs[32][NH + 1];  // +1 pad: row-varying reads below
    __shared__ float Ws[NH * NC];     // 20 KB
    int t = threadIdx.x;
    for (int i = t; i < NH * NC; i += 128) Ws[i] = Wc2[i];
    int r0 = blockIdx.x * 32;
    #pragma unroll
    for (int i = 0; i < 32; ++i) {
        int r = r0 + i;
        xs[i][t] = (r < N_NODES) ? h1[(long)r * NH + t] : 0.f;
    }
    __syncthreads();

    int r  = t >> 2;
    int c0 = (t & 3) * 10;
    float acc[10];
    #pragma unroll
    for (int i = 0; i < 10; ++i) acc[i] = 0.f;
    #pragma unroll 4
    for (int k = 0; k < NH; ++k) {
        float xv = xs[r][k];
        #pragma unroll
        for (int i = 0; i < 10; ++i) acc[i] += xv * Ws[k * NC + c0 + i];
    }
    int rr = r0 + r;
    if (rr < N_NODES) {
        #pragma unroll
        for (int i = 0; i < 10; ++i) h2[(long)rr * NC + c0 + i] = acc[i];
    }
}

// ---------------------------------------------------------------- K7: gather2 + bias + (-log_softmax), fused
// One wave per dst node; lanes 0..39 hold the 40 classes.
__global__ __launch_bounds__(256) void gather2_lsm_kernel(
    const float* __restrict__ h2, const float* __restrict__ ew,
    const int* __restrict__ src, const int* __restrict__ rp_end,
    const int* __restrict__ eids, const float* __restrict__ bc2,
    float* __restrict__ out)
{
    int wid  = (blockIdx.x * 256 + threadIdx.x) >> 6;
    int lane = threadIdx.x & 63;
    int end   = rp_end[wid];
    int start = (wid == 0) ? 0 : rp_end[wid - 1];
    float acc = 0.f;
    for (int base = start; base < end; base += 64) {
        int n = min(64, end - base);
        int s = 0; float w = 0.f;
        if (base + lane < end) {
            int e = eids[base + lane];
            s = src[e];
            w = ew[e];
        }
        #pragma unroll 4
        for (int j = 0; j < n; ++j) {
            int   sj = __shfl(s, j, 64);
            float wj = __shfl(w, j, 64);
            float v = (lane < NC) ? h2[(long)sj * NC + lane] : 0.f;
            acc += wj * v;
        }
    }
    float v = (lane < NC) ? acc + bc2[lane] : -INFINITY;
    float m = v;
    #pragma unroll
    for (int o = 32; o > 0; o >>= 1) m = fmaxf(m, __shfl_xor(m, o, 64));
    float ex = (lane < NC) ? expf(v - m) : 0.f;
    float ssum = ex;
    #pragma unroll
    for (int o = 32; o > 0; o >>= 1) ssum += __shfl_xor(ssum, o, 64);
    float lse = m + logf(ssum);
    if (lane < NC) out[(long)wid * NC + lane] = lse - v;
}

// ----------------------------------------------------------------
extern "C" void kernel_launch(void* const* d_in, const int* in_sizes, int n_in,
                              void* d_out, int out_size, void* d_ws, size_t ws_size,
                              hipStream_t stream)
{
    const float* x         = (const float*)d_in[0];
    const float* edge_feat = (const float*)d_in[1];
    const float* W1        = (const float*)d_in[2];
    const float* b1        = (const float*)d_in[3];
    const float* W2        = (const float*)d_in[4];
    const float* b2        = (const float*)d_in[5];
    const float* Wc1       = (const float*)d_in[6];
    const float* bc1       = (const float*)d_in[7];
    const float* Wc2       = (const float*)d_in[8];
    const float* bc2       = (const float*)d_in[9];
    const int*   eidx      = (const int*)d_in[10];
    const int*   dst = eidx;             // edge_index[0] (row = aggregation target)
    const int*   src = eidx + N_EDGES;   // edge_index[1]
    float* out = (float*)d_out;

    // workspace layout (16B-aligned): ew | h (reused as h2) | h1 | deg | rowptr | eids
    float* ew     = (float*)d_ws;                      // E          3.2 MB
    float* h      = ew + N_EDGES;                      // N*NH      25.6 MB
    float* h1     = h + (long)N_NODES * NH;            // N*NH      25.6 MB
    int*   deg    = (int*)(h1 + (long)N_NODES * NH);   // N          0.2 MB
    int*   rowptr = deg + N_NODES;                     // N          0.2 MB
    int*   eids   = rowptr + N_NODES;                  // E          3.2 MB
    float* h2     = h;   // h dead after gather1; reuse for h2 (N*NC = 8 MB)

    hipMemsetAsync(deg, 0, sizeof(int) * (size_t)N_NODES, stream);

    edge_mlp_kernel<<<(N_EDGES + 255) / 256, 256, 0, stream>>>(
        edge_feat, W1, b1, W2, b2, dst, ew, deg);
    gemm1_kernel<<<(N_NODES + 31) / 32, 128, 0, stream>>>(x, Wc1, h);
    build_rowptr_kernel<<<1, 1024, 0, stream>>>(deg, rowptr);
    fill_csr_kernel<<<(N_EDGES + 255) / 256, 256, 0, stream>>>(dst, rowptr, eids);
    gather1_kernel<<<(N_NODES * 64) / 256, 256, 0, stream>>>(
        h, ew, src, rowptr, eids, bc1, h1);
    gemm2_kernel<<<(N_NODES + 31) / 32, 128, 0, stream>>>(h1, Wc2, h2);
    gather2_lsm_kernel<<<(N_NODES * 64) / 256, 256, 0, stream>>>(
        h2, ew, src, rowptr, eids, bc2, out);
}

// Round 4
// 417.142 us; speedup vs baseline: 5.4088x; 1.3500x over previous
//
#include <hip/hip_runtime.h>
#include <math.h>

#define N_NODES 50000
#define N_EDGES 800000
#define DF 128
#define EF 16
#define EH 64
#define NH 128
#define NC 40
#define SCAN_B 196   // ceil(50000/256)

// ---------------------------------------------------------------- K1: edge MLP (+ fused dst-degree histogram)
// ew[e] = sigmoid( relu(ef[e]@W1 + b1) @ W2 + b2 );  deg[dst[e]] += 1
__global__ __launch_bounds__(256) void edge_mlp_kernel(
    const float* __restrict__ ef, const float* __restrict__ W1,
    const float* __restrict__ b1, const float* __restrict__ W2,
    const float* __restrict__ b2, const int* __restrict__ dst,
    float* __restrict__ ew, int* __restrict__ deg)
{
    __shared__ float4 W1s4[EF * 16];   // [k][j4] row-major view of W1[16][64]
    __shared__ float4 b1s4[16];
    __shared__ float4 W2s4[16];
    int t = threadIdx.x;
    for (int i = t; i < EF * 16; i += 256) W1s4[i] = ((const float4*)W1)[i];
    if (t < 16) { b1s4[t] = ((const float4*)b1)[t]; W2s4[t] = ((const float4*)W2)[t]; }
    __syncthreads();

    int e = blockIdx.x * 256 + t;
    if (e >= N_EDGES) return;

    float f[EF];
    const float4* ef4 = (const float4*)(ef + (long)e * EF);
    #pragma unroll
    for (int i = 0; i < 4; ++i) {
        float4 v = ef4[i];
        f[4*i+0] = v.x; f[4*i+1] = v.y; f[4*i+2] = v.z; f[4*i+3] = v.w;
    }
    float s = 0.f;
    #pragma unroll 4
    for (int jc = 0; jc < 16; ++jc) {            // 4 hidden units per chunk
        float4 a = b1s4[jc];
        #pragma unroll
        for (int k = 0; k < EF; ++k) {
            float4 w = W1s4[k * 16 + jc];        // b128 broadcast
            a.x += f[k] * w.x; a.y += f[k] * w.y;
            a.z += f[k] * w.z; a.w += f[k] * w.w;
        }
        float4 w2 = W2s4[jc];
        s += fmaxf(a.x, 0.f) * w2.x + fmaxf(a.y, 0.f) * w2.y
           + fmaxf(a.z, 0.f) * w2.z + fmaxf(a.w, 0.f) * w2.w;
    }
    s += b2[0];
    ew[e] = 1.f / (1.f + expf(-s));
    atomicAdd(&deg[dst[e]], 1);
}

// ---------------------------------------------------------------- K2: h = x @ Wc1  (register-tiled)
// 256 threads, 64-row tile; thread t: rows 8*(t>>5).., cols 4*(t&31)..
__global__ __launch_bounds__(256) void gemm1_kernel(
    const float* __restrict__ x, const float* __restrict__ Wc1,
    float* __restrict__ h)
{
    __shared__ float xs[64][DF];   // 32 KB, row-major: staging writes conflict-free
    int t = threadIdx.x;
    long r0 = (long)blockIdx.x * 64;
    for (int i = t; i < 64 * DF; i += 256) {
        int r = i >> 7, k = i & 127;
        long rr = r0 + r;
        xs[r][k] = (rr < N_NODES) ? x[rr * DF + k] : 0.f;
    }
    __syncthreads();

    int tr = t >> 5;        // 0..7  -> rows tr*8 .. +7
    int tc = t & 31;        // cols tc*4 .. +3
    float acc[8][4];
    #pragma unroll
    for (int i = 0; i < 8; ++i)
        #pragma unroll
        for (int j = 0; j < 4; ++j) acc[i][j] = 0.f;

    #pragma unroll 2
    for (int k = 0; k < DF; ++k) {
        float4 w = *(const float4*)(Wc1 + k * NH + tc * 4);  // coalesced, L1/L2
        float xv[8];
        #pragma unroll
        for (int i = 0; i < 8; ++i) xv[i] = xs[tr * 8 + i][k];  // 2-addr broadcast: free
        #pragma unroll
        for (int i = 0; i < 8; ++i) {
            acc[i][0] += xv[i] * w.x;
            acc[i][1] += xv[i] * w.y;
            acc[i][2] += xv[i] * w.z;
            acc[i][3] += xv[i] * w.w;
        }
    }
    #pragma unroll
    for (int i = 0; i < 8; ++i) {
        long r = r0 + tr * 8 + i;
        if (r < N_NODES)
            *(float4*)(h + r * NH + tc * 4) =
                make_float4(acc[i][0], acc[i][1], acc[i][2], acc[i][3]);
    }
}

// ---------------------------------------------------------------- K3a/b/c: parallel exclusive scan deg -> rowptr
__global__ __launch_bounds__(256) void scan_part_kernel(
    const int* __restrict__ deg, int* __restrict__ bsum)
{
    __shared__ int red[256];
    int t = threadIdx.x;
    int n = blockIdx.x * 256 + t;
    red[t] = (n < N_NODES) ? deg[n] : 0;
    __syncthreads();
    for (int o = 128; o > 0; o >>= 1) {
        if (t < o) red[t] += red[t + o];
        __syncthreads();
    }
    if (t == 0) bsum[blockIdx.x] = red[0];
}

__global__ __launch_bounds__(256) void scan_top_kernel(
    const int* __restrict__ bsum, int* __restrict__ boff)
{
    __shared__ int s[256];
    int t = threadIdx.x;
    s[t] = (t < SCAN_B) ? bsum[t] : 0;
    __syncthreads();
    for (int o = 1; o < 256; o <<= 1) {
        int v = (t >= o) ? s[t - o] : 0;
        __syncthreads();
        s[t] += v;
        __syncthreads();
    }
    if (t < SCAN_B) boff[t] = (t == 0) ? 0 : s[t - 1];
}

__global__ __launch_bounds__(256) void scan_write_kernel(
    const int* __restrict__ deg, const int* __restrict__ boff,
    int* __restrict__ rowptr)
{
    __shared__ int s[256];
    int t = threadIdx.x;
    int n = blockIdx.x * 256 + t;
    int v = (n < N_NODES) ? deg[n] : 0;
    s[t] = v;
    __syncthreads();
    for (int o = 1; o < 256; o <<= 1) {
        int u = (t >= o) ? s[t - o] : 0;
        __syncthreads();
        s[t] += u;
        __syncthreads();
    }
    if (n < N_NODES) rowptr[n] = boff[blockIdx.x] + s[t] - v;  // exclusive start
}

// ---------------------------------------------------------------- K4: CSR fill (payload stored in CSR order)
// Advances rowptr[d] to END of segment d; start(d) = rowptr[d-1] (0 for d=0).
__global__ __launch_bounds__(256) void fill_csr_kernel(
    const int* __restrict__ dst, const int* __restrict__ src,
    const float* __restrict__ ew, int* __restrict__ rowptr,
    int* __restrict__ csr_src, float* __restrict__ csr_ew)
{
    int e = blockIdx.x * 256 + threadIdx.x;
    if (e >= N_EDGES) return;
    int p = atomicAdd(&rowptr[dst[e]], 1);
    csr_src[p] = src[e];     // coalesced reads, scattered 4B writes
    csr_ew[p]  = ew[e];
}

// ---------------------------------------------------------------- K5: fused gather1 + gemm2
// 4 waves/block = 4 nodes. Phase1: wave gathers h1 row -> LDS. Phase2: 160 threads h2 = h1 @ Wc2.
__global__ __launch_bounds__(256) void gather1_gemm2_kernel(
    const float* __restrict__ h, const int* __restrict__ rp_end,
    const int* __restrict__ csr_src, const float* __restrict__ csr_ew,
    const float* __restrict__ bc1, const float* __restrict__ Wc2,
    float* __restrict__ h2)
{
    __shared__ float h1s[4][NH + 1];   // +1 pad: phase2 column-ish reads
    int t = threadIdx.x;
    int wv = t >> 6, lane = t & 63;
    int node = blockIdx.x * 4 + wv;    // grid = N/4 exact

    int end   = rp_end[node];
    int start = (node == 0) ? 0 : rp_end[node - 1];
    float2 acc = make_float2(0.f, 0.f);
    for (int base = start; base < end; base += 64) {
        int n = min(64, end - base);
        int s = 0; float w = 0.f;
        if (base + lane < end) {
            s = csr_src[base + lane];   // coalesced
            w = csr_ew[base + lane];
        }
        #pragma unroll 4
        for (int j = 0; j < n; ++j) {
            int   sj = __shfl(s, j, 64);
            float wj = __shfl(w, j, 64);
            float2 v = *(const float2*)(h + (long)sj * NH + lane * 2);  // 512B/edge
            acc.x += wj * v.x;
            acc.y += wj * v.y;
        }
    }
    h1s[wv][lane * 2 + 0] = fmaxf(acc.x + bc1[lane * 2 + 0], 0.f);
    h1s[wv][lane * 2 + 1] = fmaxf(acc.y + bc1[lane * 2 + 1], 0.f);
    __syncthreads();

    if (t < 4 * NC) {
        int nn = t / NC, c = t - nn * NC;
        float a0 = 0.f, a1 = 0.f;
        #pragma unroll 4
        for (int k = 0; k < NH; k += 2) {
            a0 += h1s[nn][k]     * Wc2[k * NC + c];        // Wc2: 20 KB, L1-resident
            a1 += h1s[nn][k + 1] * Wc2[(k + 1) * NC + c];
        }
        h2[(long)(blockIdx.x * 4 + nn) * NC + c] = a0 + a1;  // coalesced 640B/block
    }
}

// ---------------------------------------------------------------- K6: gather2 + bias + (-log_softmax), fused
__global__ __launch_bounds__(256) void gather2_lsm_kernel(
    const float* __restrict__ h2, const int* __restrict__ rp_end,
    const int* __restrict__ csr_src, const float* __restrict__ csr_ew,
    const float* __restrict__ bc2, float* __restrict__ out)
{
    int wid  = (blockIdx.x * 256 + threadIdx.x) >> 6;
    int lane = threadIdx.x & 63;
    int end   = rp_end[wid];
    int start = (wid == 0) ? 0 : rp_end[wid - 1];
    float acc = 0.f;
    for (int base = start; base < end; base += 64) {
        int n = min(64, end - base);
        int s = 0; float w = 0.f;
        if (base + lane < end) {
            s = csr_src[base + lane];
            w = csr_ew[base + lane];
        }
        #pragma unroll 4
        for (int j = 0; j < n; ++j) {
            int   sj = __shfl(s, j, 64);
            float wj = __shfl(w, j, 64);
            float v = (lane < NC) ? h2[(long)sj * NC + lane] : 0.f;
            acc += wj * v;
        }
    }
    float v = (lane < NC) ? acc + bc2[lane] : -INFINITY;
    float m = v;
    #pragma unroll
    for (int o = 32; o > 0; o >>= 1) m = fmaxf(m, __shfl_xor(m, o, 64));
    float ex = (lane < NC) ? expf(v - m) : 0.f;
    float ssum = ex;
    #pragma unroll
    for (int o = 32; o > 0; o >>= 1) ssum += __shfl_xor(ssum, o, 64);
    float lse = m + logf(ssum);
    if (lane < NC) out[(long)wid * NC + lane] = lse - v;
}

// ----------------------------------------------------------------
extern "C" void kernel_launch(void* const* d_in, const int* in_sizes, int n_in,
                              void* d_out, int out_size, void* d_ws, size_t ws_size,
                              hipStream_t stream)
{
    const float* x         = (const float*)d_in[0];
    const float* edge_feat = (const float*)d_in[1];
    const float* W1        = (const float*)d_in[2];
    const float* b1        = (const float*)d_in[3];
    const float* W2        = (const float*)d_in[4];
    const float* b2        = (const float*)d_in[5];
    const float* Wc1       = (const float*)d_in[6];
    const float* bc1       = (const float*)d_in[7];
    const float* Wc2       = (const float*)d_in[8];
    const float* bc2       = (const float*)d_in[9];
    const int*   eidx      = (const int*)d_in[10];
    const int*   dst = eidx;             // edge_index[0] (aggregation target)
    const int*   src = eidx + N_EDGES;   // edge_index[1]
    float* out = (float*)d_out;

    // ws layout: ew | h | h2 | csr_src | csr_ew | deg | rowptr | bsum | boff  (~44 MB)
    float* ew      = (float*)d_ws;                       // E        3.2 MB
    float* h       = ew + N_EDGES;                       // N*NH    25.6 MB
    float* h2      = h + (long)N_NODES * NH;             // N*NC     8.0 MB
    int*   csr_src = (int*)(h2 + (long)N_NODES * NC);    // E        3.2 MB
    float* csr_ew  = (float*)(csr_src + N_EDGES);        // E        3.2 MB
    int*   deg     = (int*)(csr_ew + N_EDGES);           // N        0.2 MB
    int*   rowptr  = deg + N_NODES;                      // N        0.2 MB
    int*   bsum    = rowptr + N_NODES;                   // 256
    int*   boff    = bsum + 256;                         // 256

    hipMemsetAsync(deg, 0, sizeof(int) * (size_t)N_NODES, stream);

    edge_mlp_kernel<<<(N_EDGES + 255) / 256, 256, 0, stream>>>(
        edge_feat, W1, b1, W2, b2, dst, ew, deg);
    gemm1_kernel<<<(N_NODES + 63) / 64, 256, 0, stream>>>(x, Wc1, h);
    scan_part_kernel<<<SCAN_B, 256, 0, stream>>>(deg, bsum);
    scan_top_kernel<<<1, 256, 0, stream>>>(bsum, boff);
    scan_write_kernel<<<SCAN_B, 256, 0, stream>>>(deg, boff, rowptr);
    fill_csr_kernel<<<(N_EDGES + 255) / 256, 256, 0, stream>>>(
        dst, src, ew, rowptr, csr_src, csr_ew);
    gather1_gemm2_kernel<<<N_NODES / 4, 256, 0, stream>>>(
        h, rowptr, csr_src, csr_ew, bc1, Wc2, h2);
    gather2_lsm_kernel<<<(N_NODES * 64) / 256, 256, 0, stream>>>(
        h2, rowptr, csr_src, csr_ew, bc2, out);
}

// Round 5
// 367.778 us; speedup vs baseline: 6.1348x; 1.1342x over previous
//
#include <hip/hip_runtime.h>
#include <math.h>

#define N_NODES 50000
#define N_EDGES 800000
#define DF 128
#define EF 16
#define EH 64
#define NH 128
#define NC 40
#define NCP 64       // h2 padded columns (bf16)
#define SCAN_B 196   // ceil(50000/256)

typedef __attribute__((ext_vector_type(8))) short short8v;
typedef __attribute__((ext_vector_type(4))) short short4v;

__device__ __forceinline__ float bf2f(unsigned short u) {
    union { unsigned int i; float f; } c; c.i = ((unsigned int)u) << 16; return c.f;
}
__device__ __forceinline__ unsigned short f2bf(float f) {   // round-nearest-even
    union { float f; unsigned int i; } c; c.f = f;
    unsigned int r = c.i + 0x7FFFu + ((c.i >> 16) & 1u);
    return (unsigned short)(r >> 16);
}

// ---------------------------------------------------------------- K1: edge MLP (+ fused dst-degree histogram)
__global__ __launch_bounds__(256) void edge_mlp_kernel(
    const float* __restrict__ ef, const float* __restrict__ W1,
    const float* __restrict__ b1, const float* __restrict__ W2,
    const float* __restrict__ b2, const int* __restrict__ dst,
    float* __restrict__ ew, int* __restrict__ deg)
{
    __shared__ float4 W1s4[EF * 16];   // [k][j4] view of W1[16][64]
    __shared__ float4 b1s4[16];
    __shared__ float4 W2s4[16];
    int t = threadIdx.x;
    for (int i = t; i < EF * 16; i += 256) W1s4[i] = ((const float4*)W1)[i];
    if (t < 16) { b1s4[t] = ((const float4*)b1)[t]; W2s4[t] = ((const float4*)W2)[t]; }
    __syncthreads();

    int e = blockIdx.x * 256 + t;
    if (e >= N_EDGES) return;

    float f[EF];
    const float4* ef4 = (const float4*)(ef + (long)e * EF);
    #pragma unroll
    for (int i = 0; i < 4; ++i) {
        float4 v = ef4[i];
        f[4*i+0] = v.x; f[4*i+1] = v.y; f[4*i+2] = v.z; f[4*i+3] = v.w;
    }
    float s = 0.f;
    #pragma unroll 4
    for (int jc = 0; jc < 16; ++jc) {
        float4 a = b1s4[jc];
        #pragma unroll
        for (int k = 0; k < EF; ++k) {
            float4 w = W1s4[k * 16 + jc];
            a.x += f[k] * w.x; a.y += f[k] * w.y;
            a.z += f[k] * w.z; a.w += f[k] * w.w;
        }
        float4 w2 = W2s4[jc];
        s += fmaxf(a.x, 0.f) * w2.x + fmaxf(a.y, 0.f) * w2.y
           + fmaxf(a.z, 0.f) * w2.z + fmaxf(a.w, 0.f) * w2.w;
    }
    s += b2[0];
    ew[e] = 1.f / (1.f + expf(-s));
    atomicAdd(&deg[dst[e]], 1);
}

// ---------------------------------------------------------------- K2: h = bf16(x @ Wc1)
__global__ __launch_bounds__(256) void gemm1_kernel(
    const float* __restrict__ x, const float* __restrict__ Wc1,
    unsigned short* __restrict__ hb)
{
    __shared__ float xs[64][DF];
    int t = threadIdx.x;
    long r0 = (long)blockIdx.x * 64;
    for (int i = t; i < 64 * DF; i += 256) {
        int r = i >> 7, k = i & 127;
        long rr = r0 + r;
        xs[r][k] = (rr < N_NODES) ? x[rr * DF + k] : 0.f;
    }
    __syncthreads();

    int tr = t >> 5;        // rows tr*8 .. +7
    int tc = t & 31;        // cols tc*4 .. +3
    float acc[8][4];
    #pragma unroll
    for (int i = 0; i < 8; ++i)
        #pragma unroll
        for (int j = 0; j < 4; ++j) acc[i][j] = 0.f;

    #pragma unroll 2
    for (int k = 0; k < DF; ++k) {
        float4 w = *(const float4*)(Wc1 + k * NH + tc * 4);
        float xv[8];
        #pragma unroll
        for (int i = 0; i < 8; ++i) xv[i] = xs[tr * 8 + i][k];
        #pragma unroll
        for (int i = 0; i < 8; ++i) {
            acc[i][0] += xv[i] * w.x;
            acc[i][1] += xv[i] * w.y;
            acc[i][2] += xv[i] * w.z;
            acc[i][3] += xv[i] * w.w;
        }
    }
    #pragma unroll
    for (int i = 0; i < 8; ++i) {
        long r = r0 + tr * 8 + i;
        if (r < N_NODES) {
            ushort4 sv;
            sv.x = f2bf(acc[i][0]); sv.y = f2bf(acc[i][1]);
            sv.z = f2bf(acc[i][2]); sv.w = f2bf(acc[i][3]);
            *(ushort4*)(hb + r * NH + tc * 4) = sv;
        }
    }
}

// ---------------------------------------------------------------- K3a/b/c: parallel exclusive scan deg -> rowptr
__global__ __launch_bounds__(256) void scan_part_kernel(
    const int* __restrict__ deg, int* __restrict__ bsum)
{
    __shared__ int red[256];
    int t = threadIdx.x;
    int n = blockIdx.x * 256 + t;
    red[t] = (n < N_NODES) ? deg[n] : 0;
    __syncthreads();
    for (int o = 128; o > 0; o >>= 1) {
        if (t < o) red[t] += red[t + o];
        __syncthreads();
    }
    if (t == 0) bsum[blockIdx.x] = red[0];
}

__global__ __launch_bounds__(256) void scan_top_kernel(
    const int* __restrict__ bsum, int* __restrict__ boff)
{
    __shared__ int s[256];
    int t = threadIdx.x;
    s[t] = (t < SCAN_B) ? bsum[t] : 0;
    __syncthreads();
    for (int o = 1; o < 256; o <<= 1) {
        int v = (t >= o) ? s[t - o] : 0;
        __syncthreads();
        s[t] += v;
        __syncthreads();
    }
    if (t < SCAN_B) boff[t] = (t == 0) ? 0 : s[t - 1];
}

__global__ __launch_bounds__(256) void scan_write_kernel(
    const int* __restrict__ deg, const int* __restrict__ boff,
    int* __restrict__ rowptr)
{
    __shared__ int s[256];
    int t = threadIdx.x;
    int n = blockIdx.x * 256 + t;
    int v = (n < N_NODES) ? deg[n] : 0;
    s[t] = v;
    __syncthreads();
    for (int o = 1; o < 256; o <<= 1) {
        int u = (t >= o) ? s[t - o] : 0;
        __syncthreads();
        s[t] += u;
        __syncthreads();
    }
    if (n < N_NODES) rowptr[n] = boff[blockIdx.x] + s[t] - v;
}

// ---------------------------------------------------------------- K4: CSR fill, payload packed as int2{src, ew-bits}
__global__ __launch_bounds__(256) void fill_csr_kernel(
    const int* __restrict__ dst, const int* __restrict__ src,
    const float* __restrict__ ew, int* __restrict__ rowptr,
    int2* __restrict__ csr)
{
    int e = blockIdx.x * 256 + threadIdx.x;
    if (e >= N_EDGES) return;
    int p = atomicAdd(&rowptr[dst[e]], 1);
    csr[p] = make_int2(src[e], __float_as_int(ew[e]));
}

// ---------------------------------------------------------------- K5: fused gather1 + gemm2 (1 wave = 1 node, no LDS)
// Wave = 4 groups x 16 lanes. Group g takes edge j*4+g; lane l16 loads h cols l16*8..+7 (bf16x8, 16B).
__global__ __launch_bounds__(256) void gather1_gemm2_kernel(
    const unsigned short* __restrict__ hb, const int* __restrict__ rp_end,
    const int2* __restrict__ csr, const float* __restrict__ bc1,
    const float* __restrict__ Wc2, unsigned short* __restrict__ h2b)
{
    int t = threadIdx.x;
    int node = blockIdx.x * 4 + (t >> 6);   // grid 12500*4 = 50000 exact
    int lane = t & 63;
    int l16 = lane & 15, g = lane >> 4;

    int end   = rp_end[node];
    int start = (node == 0) ? 0 : rp_end[node - 1];

    float acc[8];
    #pragma unroll
    for (int i = 0; i < 8; ++i) acc[i] = 0.f;

    for (int base = start; base < end; base += 64) {
        int n = end - base; if (n > 64) n = 64;
        int s = 0; float w = 0.f;
        if (lane < n) {
            int2 p = csr[base + lane];
            s = p.x; w = __int_as_float(p.y);
        }
        #pragma unroll 4
        for (int j = 0; j * 4 < n; ++j) {
            int idx = j * 4 + g;                       // per-lane src lane
            int   sj = __shfl(s, idx, 64);
            float wj = __shfl(w, idx, 64);             // 0 beyond n -> no contribution
            short8v hv = *(const short8v*)(hb + (long)sj * NH + l16 * 8);
            #pragma unroll
            for (int i = 0; i < 8; ++i)
                acc[i] += wj * bf2f((unsigned short)hv[i]);
        }
    }
    // sum the 4 groups' disjoint edge sets
    #pragma unroll
    for (int i = 0; i < 8; ++i) {
        acc[i] += __shfl_xor(acc[i], 16, 64);
        acc[i] += __shfl_xor(acc[i], 32, 64);
    }
    // bias + relu -> h1 cols l16*8+i (full copy in every 16-lane group)
    float4 b0 = *(const float4*)(bc1 + l16 * 8);
    float4 b1 = *(const float4*)(bc1 + l16 * 8 + 4);
    float h1v[8];
    h1v[0] = fmaxf(acc[0] + b0.x, 0.f); h1v[1] = fmaxf(acc[1] + b0.y, 0.f);
    h1v[2] = fmaxf(acc[2] + b0.z, 0.f); h1v[3] = fmaxf(acc[3] + b0.w, 0.f);
    h1v[4] = fmaxf(acc[4] + b1.x, 0.f); h1v[5] = fmaxf(acc[5] + b1.y, 0.f);
    h1v[6] = fmaxf(acc[6] + b1.z, 0.f); h1v[7] = fmaxf(acc[7] + b1.w, 0.f);

    // gemm2 in registers: h1[k] lives in lane (k>>3), elem (k&7). Wc2 is L1-resident.
    int c = (lane < NC) ? lane : (NC - 1);
    float o = 0.f;
    #pragma unroll 8
    for (int k = 0; k < NH; ++k) {
        float hk = __shfl(h1v[k & 7], k >> 3, 64);     // uniform src lane -> broadcast
        o += hk * Wc2[k * NC + c];
    }
    h2b[(long)node * NCP + lane] = f2bf((lane < NC) ? o : 0.f);  // 128B coalesced
}

// ---------------------------------------------------------------- K6: gather2 + bias + (-log_softmax) (1 wave = 1 node)
// Lane l16 owns cols l16*4..+3 of the padded-64 bf16 h2 rows.
__global__ __launch_bounds__(256) void gather2_lsm_kernel(
    const unsigned short* __restrict__ h2b, const int* __restrict__ rp_end,
    const int2* __restrict__ csr, const float* __restrict__ bc2,
    float* __restrict__ out)
{
    int t = threadIdx.x;
    int node = blockIdx.x * 4 + (t >> 6);
    int lane = t & 63;
    int l16 = lane & 15, g = lane >> 4;

    int end   = rp_end[node];
    int start = (node == 0) ? 0 : rp_end[node - 1];

    float acc[4];
    #pragma unroll
    for (int i = 0; i < 4; ++i) acc[i] = 0.f;

    for (int base = start; base < end; base += 64) {
        int n = end - base; if (n > 64) n = 64;
        int s = 0; float w = 0.f;
        if (lane < n) {
            int2 p = csr[base + lane];
            s = p.x; w = __int_as_float(p.y);
        }
        #pragma unroll 4
        for (int j = 0; j * 4 < n; ++j) {
            int idx = j * 4 + g;
            int   sj = __shfl(s, idx, 64);
            float wj = __shfl(w, idx, 64);
            short4v hv = *(const short4v*)(h2b + (long)sj * NCP + l16 * 4);
            #pragma unroll
            for (int i = 0; i < 4; ++i)
                acc[i] += wj * bf2f((unsigned short)hv[i]);
        }
    }
    #pragma unroll
    for (int i = 0; i < 4; ++i) {
        acc[i] += __shfl_xor(acc[i], 16, 64);
        acc[i] += __shfl_xor(acc[i], 32, 64);
    }

    // bias + masked log-softmax over cols l16*4+i (valid iff l16 < 10; 40%4==0)
    bool valid = (l16 < 10);
    float4 bcv = valid ? *(const float4*)(bc2 + l16 * 4) : make_float4(0.f, 0.f, 0.f, 0.f);
    float v[4];
    v[0] = acc[0] + bcv.x; v[1] = acc[1] + bcv.y;
    v[2] = acc[2] + bcv.z; v[3] = acc[3] + bcv.w;

    float mx = valid ? fmaxf(fmaxf(v[0], v[1]), fmaxf(v[2], v[3])) : -INFINITY;
    #pragma unroll
    for (int o = 1; o <= 8; o <<= 1) mx = fmaxf(mx, __shfl_xor(mx, o, 64));
    float se = 0.f;
    if (valid) se = expf(v[0]-mx) + expf(v[1]-mx) + expf(v[2]-mx) + expf(v[3]-mx);
    #pragma unroll
    for (int o = 1; o <= 8; o <<= 1) se += __shfl_xor(se, o, 64);
    float lse = mx + logf(se);

    if (valid && g == 0) {
        float4 r = make_float4(lse - v[0], lse - v[1], lse - v[2], lse - v[3]);
        *(float4*)(out + (long)node * NC + l16 * 4) = r;   // 160B/row, 16B aligned
    }
}

// ----------------------------------------------------------------
extern "C" void kernel_launch(void* const* d_in, const int* in_sizes, int n_in,
                              void* d_out, int out_size, void* d_ws, size_t ws_size,
                              hipStream_t stream)
{
    const float* x         = (const float*)d_in[0];
    const float* edge_feat = (const float*)d_in[1];
    const float* W1        = (const float*)d_in[2];
    const float* b1        = (const float*)d_in[3];
    const float* W2        = (const float*)d_in[4];
    const float* b2        = (const float*)d_in[5];
    const float* Wc1       = (const float*)d_in[6];
    const float* bc1       = (const float*)d_in[7];
    const float* Wc2       = (const float*)d_in[8];
    const float* bc2       = (const float*)d_in[9];
    const int*   eidx      = (const int*)d_in[10];
    const int*   dst = eidx;             // edge_index[0] (aggregation target)
    const int*   src = eidx + N_EDGES;   // edge_index[1]
    float* out = (float*)d_out;

    // ws layout: ew | hb(bf16) | h2b(bf16,pad64) | csr(int2) | deg | rowptr | bsum | boff  (~29 MB)
    float*          ew     = (float*)d_ws;                       // E        3.2 MB
    unsigned short* hb     = (unsigned short*)(ew + N_EDGES);    // N*NH*2  12.8 MB
    unsigned short* h2b    = hb + (long)N_NODES * NH;            // N*64*2   6.4 MB
    int2*           csr    = (int2*)(h2b + (long)N_NODES * NCP); // E*8      6.4 MB
    int*            deg    = (int*)(csr + N_EDGES);              // N        0.2 MB
    int*            rowptr = deg + N_NODES;                      // N        0.2 MB
    int*            bsum   = rowptr + N_NODES;                   // 256
    int*            boff   = bsum + 256;                         // 256

    hipMemsetAsync(deg, 0, sizeof(int) * (size_t)N_NODES, stream);

    edge_mlp_kernel<<<(N_EDGES + 255) / 256, 256, 0, stream>>>(
        edge_feat, W1, b1, W2, b2, dst, ew, deg);
    gemm1_kernel<<<(N_NODES + 63) / 64, 256, 0, stream>>>(x, Wc1, hb);
    scan_part_kernel<<<SCAN_B, 256, 0, stream>>>(deg, bsum);
    scan_top_kernel<<<1, 256, 0, stream>>>(bsum, boff);
    scan_write_kernel<<<SCAN_B, 256, 0, stream>>>(deg, boff, rowptr);
    fill_csr_kernel<<<(N_EDGES + 255) / 256, 256, 0, stream>>>(
        dst, src, ew, rowptr, csr);
    gather1_gemm2_kernel<<<N_NODES / 4, 256, 0, stream>>>(
        hb, rowptr, csr, bc1, Wc2, h2b);
    gather2_lsm_kernel<<<N_NODES / 4, 256, 0, stream>>>(
        h2b, rowptr, csr, bc2, out);
}